// Round 2
// baseline (1668.951 us; speedup 1.0000x reference)
//
#include <hip/hip_runtime.h>

// AttentionBlock: GroupNorm -> QKV 1x1 -> 8-head attention (L=1024) -> proj -> residual
// B=16, C=512, H=W=32 (L=1024), 32 groups (16 ch/group), 8 heads (ch=64)
// All inputs/outputs fp32 (per reference dtypes). fp32 accumulation throughout.

#define BATCH 16
#define CDIM 512
#define LDIM 1024
#define GROUPS 32
#define CPG 16
#define NHEADS 8
#define CH 64
#define TT 4  // t-columns per attention block

// ---------------- GroupNorm stats: one block per (b,g); emit per-channel scale/shift --------
__global__ __launch_bounds__(256) void gn_stats_kernel(const float* __restrict__ x,
                                                       const float* __restrict__ w,
                                                       const float* __restrict__ bvec,
                                                       float* __restrict__ scl,
                                                       float* __restrict__ sh) {
  int bg = blockIdx.x;
  int bb = bg >> 5, g = bg & 31;
  size_t base = ((size_t)bb * CDIM + g * CPG) * LDIM;
  const float4* x4 = (const float4*)(x + base);
  int tid = threadIdx.x;
  float sum = 0.f, ss = 0.f;
#pragma unroll
  for (int i = 0; i < 16; ++i) {  // 16 ch * 1024 = 4096 float4
    float4 v = x4[tid + 256 * i];
    sum += v.x + v.y + v.z + v.w;
    ss += v.x * v.x + v.y * v.y + v.z * v.z + v.w * v.w;
  }
#pragma unroll
  for (int off = 32; off; off >>= 1) {
    sum += __shfl_xor(sum, off);
    ss += __shfl_xor(ss, off);
  }
  __shared__ float rs[4], rq[4];
  int lane = tid & 63, wv = tid >> 6;
  if (lane == 0) { rs[wv] = sum; rq[wv] = ss; }
  __syncthreads();
  sum = rs[0] + rs[1] + rs[2] + rs[3];
  ss = rq[0] + rq[1] + rq[2] + rq[3];
  const float inv_n = 1.f / (float)(CPG * LDIM);
  float mean = sum * inv_n;
  float var = ss * inv_n - mean * mean;
  float rstd = rsqrtf(var + 1e-4f);
  if (tid < CPG) {
    int c = g * CPG + tid;
    float s = w[c] * rstd;
    scl[bb * CDIM + c] = s;
    sh[bb * CDIM + c] = bvec[c] - mean * s;
  }
}

// ---------------- Tiled GEMM: Out[b][m][n] = sum_c W[m][c]*B[b][c][n] + bias[m] -------------
// Optional fused GroupNorm on B (scl/sh per (b,c)); optional residual add on output.
// 64x64 tile, BK=16, 256 threads, 4x4 microtile, fp32.
template <int FUSE_GN, int ADD_RES>
__global__ __launch_bounds__(256) void gemm_kernel(const float* __restrict__ W,
                                                   const float* __restrict__ bias,
                                                   const float* __restrict__ Bmat,
                                                   const float* __restrict__ scl,
                                                   const float* __restrict__ sh,
                                                   const float* __restrict__ resid,
                                                   float* __restrict__ Out, int M) {
  const int KD = 512;
  int bb = blockIdx.z;
  int m0 = blockIdx.y * 64;
  int n0 = blockIdx.x * 64;
  int tid = threadIdx.x;
  __shared__ float As[16][68];  // [k][m], pad keeps float4 alignment (68*4=272=17*16)
  __shared__ float Bs[16][68];  // [k][n]
  const float* Bp = Bmat + (size_t)bb * KD * LDIM;
  float acc[4][4] = {};
  int tx = tid & 15, ty = tid >> 4;
  int ar = tid >> 2, ac4 = (tid & 3) * 4;   // A: 64 rows x 16 k
  int bk = tid >> 4, bn4 = (tid & 15) * 4;  // B: 16 k x 64 n
  for (int kk = 0; kk < KD; kk += 16) {
    float4 av = *(const float4*)&W[(size_t)(m0 + ar) * KD + kk + ac4];
    float4 bv = *(const float4*)&Bp[(size_t)(kk + bk) * LDIM + n0 + bn4];
    float s_ = 1.f, h_ = 0.f;
    if (FUSE_GN) {
      s_ = scl[bb * CDIM + kk + bk];
      h_ = sh[bb * CDIM + kk + bk];
    }
    __syncthreads();
    As[ac4 + 0][ar] = av.x;
    As[ac4 + 1][ar] = av.y;
    As[ac4 + 2][ar] = av.z;
    As[ac4 + 3][ar] = av.w;
    if (FUSE_GN) {
      Bs[bk][bn4 + 0] = bv.x * s_ + h_;
      Bs[bk][bn4 + 1] = bv.y * s_ + h_;
      Bs[bk][bn4 + 2] = bv.z * s_ + h_;
      Bs[bk][bn4 + 3] = bv.w * s_ + h_;
    } else {
      Bs[bk][bn4 + 0] = bv.x;
      Bs[bk][bn4 + 1] = bv.y;
      Bs[bk][bn4 + 2] = bv.z;
      Bs[bk][bn4 + 3] = bv.w;
    }
    __syncthreads();
#pragma unroll
    for (int k = 0; k < 16; ++k) {
      float4 a4 = *(const float4*)&As[k][ty * 4];
      float4 b4 = *(const float4*)&Bs[k][tx * 4];
      float a[4] = {a4.x, a4.y, a4.z, a4.w};
      float b[4] = {b4.x, b4.y, b4.z, b4.w};
#pragma unroll
      for (int i = 0; i < 4; ++i)
#pragma unroll
        for (int j = 0; j < 4; ++j) acc[i][j] += a[i] * b[j];
    }
  }
#pragma unroll
  for (int i = 0; i < 4; ++i) {
    int m = m0 + ty * 4 + i;
    float bias_v = bias[m];
    size_t off = ((size_t)bb * M + m) * LDIM + n0 + tx * 4;
    float4 o;
    o.x = acc[i][0] + bias_v;
    o.y = acc[i][1] + bias_v;
    o.z = acc[i][2] + bias_v;
    o.w = acc[i][3] + bias_v;
    if (ADD_RES) {
      float4 xv = *(const float4*)&resid[off];
      o.x += xv.x; o.y += xv.y; o.z += xv.z; o.w += xv.w;
    }
    *(float4*)&Out[off] = o;
  }
}

// ---------------- Attention: one block per (bh, 4 t-columns) ----------------
// scores[t,s] = sum_c q[c,t]k[c,s]/8 ; softmax over s ; a[c,t] = sum_s p[s]v[c,s]
__global__ __launch_bounds__(256) void attn_kernel(const float* __restrict__ qkv,
                                                   float* __restrict__ aout) {
  int t0 = blockIdx.x * TT;
  int bh = blockIdx.y;
  int bb = bh >> 3, h = bh & 7;
  size_t base = ((size_t)bb * 3 * CDIM + h * CH) * LDIM;
  const float* qb = qkv + base;
  const float* kb = qkv + base + (size_t)CDIM * LDIM;
  const float* vb = qkv + base + (size_t)2 * CDIM * LDIM;
  __shared__ float qs[TT][CH];
  __shared__ float ps[TT][LDIM];      // 16 KB probs
  __shared__ float redm[4][TT];
  __shared__ float reds[4][TT];
  __shared__ float pvred[4][CH][TT];  // 4 KB partial PV
  int tid = threadIdx.x;
  int lane = tid & 63, wv = tid >> 6;
  {
    int c = tid & 63, tt = tid >> 6;
    qs[tt][c] = qb[(size_t)c * LDIM + t0 + tt];
  }
  __syncthreads();
  int s4 = tid * 4;  // each thread owns 4 consecutive s
  float sc[TT][4];
#pragma unroll
  for (int tt = 0; tt < TT; ++tt)
#pragma unroll
    for (int j = 0; j < 4; ++j) sc[tt][j] = 0.f;
  for (int c = 0; c < CH; ++c) {
    float4 kv = *(const float4*)&kb[(size_t)c * LDIM + s4];
#pragma unroll
    for (int tt = 0; tt < TT; ++tt) {
      float q = qs[tt][c];
      sc[tt][0] += q * kv.x;
      sc[tt][1] += q * kv.y;
      sc[tt][2] += q * kv.z;
      sc[tt][3] += q * kv.w;
    }
  }
  float rowmax[TT], inv_sum[TT];
#pragma unroll
  for (int tt = 0; tt < TT; ++tt) {
#pragma unroll
    for (int j = 0; j < 4; ++j) sc[tt][j] *= 0.125f;  // ch^-0.5
    float m = fmaxf(fmaxf(sc[tt][0], sc[tt][1]), fmaxf(sc[tt][2], sc[tt][3]));
#pragma unroll
    for (int off = 32; off; off >>= 1) m = fmaxf(m, __shfl_xor(m, off));
    if (lane == 0) redm[wv][tt] = m;
  }
  __syncthreads();
#pragma unroll
  for (int tt = 0; tt < TT; ++tt) {
    rowmax[tt] = fmaxf(fmaxf(redm[0][tt], redm[1][tt]), fmaxf(redm[2][tt], redm[3][tt]));
    float4 p;
    p.x = __expf(sc[tt][0] - rowmax[tt]);
    p.y = __expf(sc[tt][1] - rowmax[tt]);
    p.z = __expf(sc[tt][2] - rowmax[tt]);
    p.w = __expf(sc[tt][3] - rowmax[tt]);
    *(float4*)&ps[tt][s4] = p;
    float lsum = p.x + p.y + p.z + p.w;
#pragma unroll
    for (int off = 32; off; off >>= 1) lsum += __shfl_xor(lsum, off);
    if (lane == 0) reds[wv][tt] = lsum;
  }
  __syncthreads();
#pragma unroll
  for (int tt = 0; tt < TT; ++tt)
    inv_sum[tt] = 1.f / (reds[0][tt] + reds[1][tt] + reds[2][tt] + reds[3][tt]);
  // PV: thread (c = tid>>2, part = tid&3) sums 256 s values
  int c = tid >> 2, part = tid & 3;
  float acc[TT] = {0.f, 0.f, 0.f, 0.f};
  int sbeg = part * 256;
  for (int s = sbeg; s < sbeg + 256; s += 4) {
    float4 vv = *(const float4*)&vb[(size_t)c * LDIM + s];
#pragma unroll
    for (int tt = 0; tt < TT; ++tt) {
      float4 p = *(const float4*)&ps[tt][s];
      acc[tt] += p.x * vv.x + p.y * vv.y + p.z * vv.z + p.w * vv.w;
    }
  }
#pragma unroll
  for (int tt = 0; tt < TT; ++tt) pvred[part][c][tt] = acc[tt];
  __syncthreads();
  if (tid < CH) {
    int cc = tid;
    float4 o;
    float v0 = pvred[0][cc][0] + pvred[1][cc][0] + pvred[2][cc][0] + pvred[3][cc][0];
    float v1 = pvred[0][cc][1] + pvred[1][cc][1] + pvred[2][cc][1] + pvred[3][cc][1];
    float v2 = pvred[0][cc][2] + pvred[1][cc][2] + pvred[2][cc][2] + pvred[3][cc][2];
    float v3 = pvred[0][cc][3] + pvred[1][cc][3] + pvred[2][cc][3] + pvred[3][cc][3];
    o.x = v0 * inv_sum[0];
    o.y = v1 * inv_sum[1];
    o.z = v2 * inv_sum[2];
    o.w = v3 * inv_sum[3];
    size_t off = ((size_t)bb * CDIM + h * CH + cc) * LDIM + t0;
    *(float4*)&aout[off] = o;
  }
}

extern "C" void kernel_launch(void* const* d_in, const int* in_sizes, int n_in,
                              void* d_out, int out_size, void* d_ws, size_t ws_size,
                              hipStream_t stream) {
  const float* x = (const float*)d_in[0];
  const float* norm_w = (const float*)d_in[1];
  const float* norm_b = (const float*)d_in[2];
  const float* qkv_w = (const float*)d_in[3];
  const float* qkv_b = (const float*)d_in[4];
  const float* proj_w = (const float*)d_in[5];
  const float* proj_b = (const float*)d_in[6];
  float* out = (float*)d_out;

  float* scl = (float*)d_ws;                           // [B][C]      : 32 KB
  float* sh = scl + (size_t)BATCH * CDIM;              // [B][C]      : 32 KB
  float* qkvb = sh + (size_t)BATCH * CDIM;             // [B][3C][L]  : 100.7 MB
  float* av = qkvb + (size_t)BATCH * 3 * CDIM * LDIM;  // [B][C][L]   : 33.5 MB

  gn_stats_kernel<<<dim3(BATCH * GROUPS), dim3(256), 0, stream>>>(x, norm_w, norm_b, scl, sh);
  gemm_kernel<1, 0><<<dim3(LDIM / 64, (3 * CDIM) / 64, BATCH), dim3(256), 0, stream>>>(
      qkv_w, qkv_b, x, scl, sh, (const float*)nullptr, qkvb, 3 * CDIM);
  attn_kernel<<<dim3(LDIM / TT, BATCH * NHEADS), dim3(256), 0, stream>>>(qkvb, av);
  gemm_kernel<0, 1><<<dim3(LDIM / 64, CDIM / 64, BATCH), dim3(256), 0, stream>>>(
      proj_w, proj_b, av, (const float*)nullptr, (const float*)nullptr, x, out, CDIM);
}

// Round 3
// 319.365 us; speedup vs baseline: 5.2258x; 5.2258x over previous
//
#include <hip/hip_runtime.h>
#include <cmath>

// AttentionBlock: GroupNorm -> QKV 1x1 -> 8-head attention (L=1024) -> proj -> residual
// B=16, C=512, L=1024, 32 groups, 8 heads (ch=64). fp32 in/out, bf16 MFMA internally.

#define BATCH 16
#define CDIM 512
#define LDIM 1024

typedef unsigned short u16;
typedef u16 ushort8v __attribute__((ext_vector_type(8)));
typedef __bf16 bf16x8_t __attribute__((ext_vector_type(8)));
typedef float f32x4 __attribute__((ext_vector_type(4)));

__device__ __forceinline__ u16 f2bf(float f) {
  unsigned u = __float_as_uint(f);
  unsigned r = u + 0x7fffu + ((u >> 16) & 1u);  // RNE
  return (u16)(r >> 16);
}
__device__ __forceinline__ unsigned pack2(float a, float b) {
  return (unsigned)f2bf(a) | ((unsigned)f2bf(b) << 16);
}
__device__ __forceinline__ f32x4 mfma16(ushort8v a, ushort8v b, f32x4 c) {
  return __builtin_amdgcn_mfma_f32_16x16x32_bf16(
      __builtin_bit_cast(bf16x8_t, a), __builtin_bit_cast(bf16x8_t, b), c, 0, 0, 0);
}

// ---------------- GroupNorm stats: per-(b,c) scale/shift ----------------
__global__ __launch_bounds__(256) void gn_stats_kernel(const float* __restrict__ x,
                                                       const float* __restrict__ w,
                                                       const float* __restrict__ bvec,
                                                       float* __restrict__ scl,
                                                       float* __restrict__ sh) {
  int bg = blockIdx.x;
  int bb = bg >> 5, g = bg & 31;
  size_t base = ((size_t)bb * CDIM + g * 16) * LDIM;
  const float4* x4 = (const float4*)(x + base);
  int tid = threadIdx.x;
  float sum = 0.f, ss = 0.f;
#pragma unroll
  for (int i = 0; i < 16; ++i) {
    float4 v = x4[tid + 256 * i];
    sum += v.x + v.y + v.z + v.w;
    ss += v.x * v.x + v.y * v.y + v.z * v.z + v.w * v.w;
  }
#pragma unroll
  for (int off = 32; off; off >>= 1) {
    sum += __shfl_xor(sum, off);
    ss += __shfl_xor(ss, off);
  }
  __shared__ float rs[4], rq[4];
  int lane = tid & 63, wv = tid >> 6;
  if (lane == 0) { rs[wv] = sum; rq[wv] = ss; }
  __syncthreads();
  sum = rs[0] + rs[1] + rs[2] + rs[3];
  ss = rq[0] + rq[1] + rq[2] + rq[3];
  const float inv_n = 1.f / (16.f * 1024.f);
  float mean = sum * inv_n;
  float var = ss * inv_n - mean * mean;
  float rstd = rsqrtf(var + 1e-4f);
  if (tid < 16) {
    int c = g * 16 + tid;
    float s = w[c] * rstd;
    scl[bb * CDIM + c] = s;
    sh[bb * CDIM + c] = bvec[c] - mean * s;
  }
}

// ---------------- MFMA GEMM, 128x128 tile, BK=32 ----------------
// MODE 0: QK rows -> transposed output qt/kt[bh][t][c] bf16 (Q scaled by 0.125)
// MODE 1: V rows  -> v[b][c][l] bf16
// MODE 2: proj    -> fp32 out + bias + residual (B input = av bf16)
template <int MODE>
__global__ __launch_bounds__(256) void gemm_mfma(
    const float* __restrict__ Wg, const float* __restrict__ biasg,
    const float* __restrict__ Xf, const u16* __restrict__ Xb,
    const float* __restrict__ scl, const float* __restrict__ sh,
    const float* __restrict__ resid,
    u16* __restrict__ qo, u16* __restrict__ ko,
    u16* __restrict__ vo, float* __restrict__ fo, int m_base) {
  __shared__ __align__(16) u16 Ws[128][40];  // [m][k], pad 40
  __shared__ __align__(16) u16 Xs[128][40];  // [n][k]
  int bb = blockIdx.z;
  int m0 = m_base + blockIdx.y * 128;
  int n0 = blockIdx.x * 128;
  int tid = threadIdx.x;
  int w = tid >> 6, lane = tid & 63, quad = lane >> 4, l15 = lane & 15;
  int wm = (w >> 1) * 64, wn = (w & 1) * 64;
  f32x4 acc[4][4] = {};  // MODE0: [nsub][msub]; else: [msub][nsub]
  int xkb = tid >> 5, xnb = tid & 31;

  for (int kk = 0; kk < 512; kk += 32) {
    float4 wv[4];
#pragma unroll
    for (int r = 0; r < 4; ++r) {
      int f = tid + 256 * r;
      wv[r] = *(const float4*)&Wg[(size_t)(m0 + (f >> 3)) * 512 + kk + (f & 7) * 4];
    }
    uint2 xw[4];
    if (MODE != 2) {
      float4 xv[4];
#pragma unroll
      for (int r = 0; r < 4; ++r) {
        int kch = kk + xkb * 4 + r;
        float s_ = scl[bb * CDIM + kch];
        float h_ = sh[bb * CDIM + kch];
        float4 t = *(const float4*)&Xf[((size_t)bb * CDIM + kch) * LDIM + n0 + xnb * 4];
        xv[r] = make_float4(t.x * s_ + h_, t.y * s_ + h_, t.z * s_ + h_, t.w * s_ + h_);
      }
#pragma unroll
      for (int j = 0; j < 4; ++j) {
        const float* p0 = (const float*)&xv[0];
        const float* p1 = (const float*)&xv[1];
        const float* p2 = (const float*)&xv[2];
        const float* p3 = (const float*)&xv[3];
        xw[j].x = pack2(p0[j], p1[j]);
        xw[j].y = pack2(p2[j], p3[j]);
      }
    } else {
      ushort4 xu[4];
#pragma unroll
      for (int r = 0; r < 4; ++r)
        xu[r] = *(const ushort4*)&Xb[((size_t)bb * CDIM + kk + xkb * 4 + r) * LDIM + n0 + xnb * 4];
#pragma unroll
      for (int j = 0; j < 4; ++j) {
        const u16* p0 = (const u16*)&xu[0];
        const u16* p1 = (const u16*)&xu[1];
        const u16* p2 = (const u16*)&xu[2];
        const u16* p3 = (const u16*)&xu[3];
        xw[j].x = (unsigned)p0[j] | ((unsigned)p1[j] << 16);
        xw[j].y = (unsigned)p2[j] | ((unsigned)p3[j] << 16);
      }
    }
    __syncthreads();
#pragma unroll
    for (int r = 0; r < 4; ++r) {
      int f = tid + 256 * r;
      uint2 u;
      u.x = pack2(wv[r].x, wv[r].y);
      u.y = pack2(wv[r].z, wv[r].w);
      *(uint2*)&Ws[f >> 3][(f & 7) * 4] = u;
    }
#pragma unroll
    for (int j = 0; j < 4; ++j) *(uint2*)&Xs[xnb * 4 + j][xkb * 4] = xw[j];
    __syncthreads();
    ushort8v af[4], bfr[4];
#pragma unroll
    for (int i = 0; i < 4; ++i) af[i] = *(const ushort8v*)&Ws[wm + i * 16 + l15][quad * 8];
#pragma unroll
    for (int i = 0; i < 4; ++i) bfr[i] = *(const ushort8v*)&Xs[wn + i * 16 + l15][quad * 8];
#pragma unroll
    for (int i = 0; i < 4; ++i)
#pragma unroll
      for (int j = 0; j < 4; ++j) {
        if (MODE == 0)
          acc[j][i] = mfma16(bfr[j], af[i], acc[j][i]);  // D[n][m]
        else
          acc[i][j] = mfma16(af[i], bfr[j], acc[i][j]);  // D[m][n]
      }
  }

  if (MODE == 0) {
    bool isQ = (m0 < 512);
    float qscale = isQ ? 0.125f : 1.0f;
    u16* dst = isQ ? qo : ko;
    int cbase0 = m0 - (isQ ? 0 : 512) + wm;
#pragma unroll
    for (int i = 0; i < 4; ++i) {
      int cg = cbase0 + i * 16 + l15;
      float bv = biasg[m0 + wm + i * 16 + l15];
      int hh = cg >> 6, cl = cg & 63;
      size_t rowbase = ((size_t)(bb * 8 + hh) * 1024) * 64 + cl;
#pragma unroll
      for (int j = 0; j < 4; ++j)
#pragma unroll
        for (int r = 0; r < 4; ++r) {
          int t = n0 + wn + j * 16 + quad * 4 + r;
          dst[rowbase + (size_t)t * 64] = f2bf((acc[j][i][r] + bv) * qscale);
        }
    }
  } else if (MODE == 1) {
#pragma unroll
    for (int i = 0; i < 4; ++i)
#pragma unroll
      for (int r = 0; r < 4; ++r) {
        int m_abs = m0 + wm + i * 16 + quad * 4 + r;
        float bv = biasg[m_abs];
        int cg = m_abs - 1024;
#pragma unroll
        for (int j = 0; j < 4; ++j) {
          int n = n0 + wn + j * 16 + l15;
          vo[((size_t)bb * CDIM + cg) * LDIM + n] = f2bf(acc[i][j][r] + bv);
        }
      }
  } else {
#pragma unroll
    for (int i = 0; i < 4; ++i)
#pragma unroll
      for (int r = 0; r < 4; ++r) {
        int m_abs = m0 + wm + i * 16 + quad * 4 + r;
        float bv = biasg[m_abs];
#pragma unroll
        for (int j = 0; j < 4; ++j) {
          int n = n0 + wn + j * 16 + l15;
          size_t off = ((size_t)bb * CDIM + m_abs) * LDIM + n;
          fo[off] = acc[i][j][r] + bv + resid[off];
        }
      }
  }
}

// ---------------- Flash attention, MFMA ----------------
// Block: 4 waves x 32 t = 128 t, one bh. s-tiles of 32.
// QK computes S^T (s rows, t cols) so softmax reduce over s is in-register + 2 shuffles.
__global__ __launch_bounds__(256) void attn_mfma(const u16* __restrict__ qt,
                                                 const u16* __restrict__ kt,
                                                 const u16* __restrict__ vv,
                                                 u16* __restrict__ av_out) {
  __shared__ __align__(16) u16 Ps[4][32][40];  // per-wave P tile [t][s], pad 40
  int t0b = blockIdx.x * 128;
  int bh = blockIdx.y;
  int b = bh >> 3, h = bh & 7;
  int tid = threadIdx.x;
  int w = tid >> 6, lane = tid & 63, quad = lane >> 4, l15 = lane & 15;
  int t0w = t0b + w * 32;
  size_t head = (size_t)bh * 65536;  // 1024*64

  ushort8v qf[2][2];
#pragma unroll
  for (int ts = 0; ts < 2; ++ts)
#pragma unroll
    for (int kc = 0; kc < 2; ++kc)
      qf[ts][kc] =
          *(const ushort8v*)&qt[head + (size_t)(t0w + ts * 16 + l15) * 64 + kc * 32 + quad * 8];

  f32x4 Co[4][2] = {};
  float mrun[2] = {-INFINITY, -INFINITY}, lrun[2] = {0.f, 0.f};

  for (int s0 = 0; s0 < 1024; s0 += 32) {
    ushort8v kf[2][2];
#pragma unroll
    for (int ms = 0; ms < 2; ++ms)
#pragma unroll
      for (int kc = 0; kc < 2; ++kc)
        kf[ms][kc] =
            *(const ushort8v*)&kt[head + (size_t)(s0 + ms * 16 + l15) * 64 + kc * 32 + quad * 8];
    f32x4 st[2][2];  // [tsub][msub]; rows = s, cols = t
#pragma unroll
    for (int ts = 0; ts < 2; ++ts)
#pragma unroll
      for (int ms = 0; ms < 2; ++ms) {
        f32x4 z = {};
        z = mfma16(kf[ms][0], qf[ts][0], z);
        st[ts][ms] = mfma16(kf[ms][1], qf[ts][1], z);
      }
#pragma unroll
    for (int ts = 0; ts < 2; ++ts) {
      f32x4 s0v = st[ts][0], s1v = st[ts][1];
      float mx = fmaxf(fmaxf(fmaxf(s0v.x, s0v.y), fmaxf(s0v.z, s0v.w)),
                       fmaxf(fmaxf(s1v.x, s1v.y), fmaxf(s1v.z, s1v.w)));
      mx = fmaxf(mx, __shfl_xor(mx, 16));
      mx = fmaxf(mx, __shfl_xor(mx, 32));
      float mnew = fmaxf(mrun[ts], mx);
      float alpha = __expf(mrun[ts] - mnew);
      mrun[ts] = mnew;
      float p0 = __expf(s0v.x - mnew), p1 = __expf(s0v.y - mnew);
      float p2 = __expf(s0v.z - mnew), p3 = __expf(s0v.w - mnew);
      float p4 = __expf(s1v.x - mnew), p5 = __expf(s1v.y - mnew);
      float p6 = __expf(s1v.z - mnew), p7 = __expf(s1v.w - mnew);
      float tl = ((p0 + p1) + (p2 + p3)) + ((p4 + p5) + (p6 + p7));
      tl += __shfl_xor(tl, 16);
      tl += __shfl_xor(tl, 32);
      lrun[ts] = lrun[ts] * alpha + tl;
#pragma unroll
      for (int cs = 0; cs < 4; ++cs) Co[cs][ts] *= alpha;
      uint2 u0, u1;
      u0.x = pack2(p0, p1);
      u0.y = pack2(p2, p3);
      u1.x = pack2(p4, p5);
      u1.y = pack2(p6, p7);
      *(uint2*)&Ps[w][ts * 16 + l15][quad * 4] = u0;
      *(uint2*)&Ps[w][ts * 16 + l15][16 + quad * 4] = u1;
    }
    __syncthreads();
    ushort8v pb[2];
#pragma unroll
    for (int ts = 0; ts < 2; ++ts) pb[ts] = *(const ushort8v*)&Ps[w][ts * 16 + l15][quad * 8];
    ushort8v vf[4];
#pragma unroll
    for (int cs = 0; cs < 4; ++cs)
      vf[cs] = *(const ushort8v*)&vv[head + (size_t)(cs * 16 + l15) * 1024 + s0 + quad * 8];
#pragma unroll
    for (int cs = 0; cs < 4; ++cs)
#pragma unroll
      for (int ts = 0; ts < 2; ++ts) Co[cs][ts] = mfma16(vf[cs], pb[ts], Co[cs][ts]);
  }
  float inv[2] = {1.f / lrun[0], 1.f / lrun[1]};
#pragma unroll
  for (int cs = 0; cs < 4; ++cs)
#pragma unroll
    for (int ts = 0; ts < 2; ++ts) {
      int t = t0w + ts * 16 + l15;
#pragma unroll
      for (int r = 0; r < 4; ++r) {
        int c = h * 64 + cs * 16 + quad * 4 + r;
        av_out[((size_t)b * CDIM + c) * LDIM + t] = f2bf(Co[cs][ts][r] * inv[ts]);
      }
    }
}

extern "C" void kernel_launch(void* const* d_in, const int* in_sizes, int n_in,
                              void* d_out, int out_size, void* d_ws, size_t ws_size,
                              hipStream_t stream) {
  const float* x = (const float*)d_in[0];
  const float* norm_w = (const float*)d_in[1];
  const float* norm_b = (const float*)d_in[2];
  const float* qkv_w = (const float*)d_in[3];
  const float* qkv_b = (const float*)d_in[4];
  const float* proj_w = (const float*)d_in[5];
  const float* proj_b = (const float*)d_in[6];
  float* out = (float*)d_out;

  const size_t NE = (size_t)BATCH * CDIM * LDIM;  // 8.39M
  float* scl = (float*)d_ws;
  float* sh = scl + BATCH * CDIM;
  u16* qt = (u16*)(sh + BATCH * CDIM);  // [bh][t][c] bf16
  u16* kt = qt + NE;                    // [bh][s][c] bf16
  u16* vv = kt + NE;                    // [b][c][l]  bf16
  u16* av = vv + NE;                    // [b][c][l]  bf16

  gn_stats_kernel<<<dim3(BATCH * 32), dim3(256), 0, stream>>>(x, norm_w, norm_b, scl, sh);
  gemm_mfma<0><<<dim3(8, 8, BATCH), dim3(256), 0, stream>>>(
      qkv_w, qkv_b, x, (const u16*)nullptr, scl, sh, (const float*)nullptr,
      qt, kt, (u16*)nullptr, (float*)nullptr, 0);
  gemm_mfma<1><<<dim3(8, 4, BATCH), dim3(256), 0, stream>>>(
      qkv_w, qkv_b, x, (const u16*)nullptr, scl, sh, (const float*)nullptr,
      (u16*)nullptr, (u16*)nullptr, vv, (float*)nullptr, 1024);
  attn_mfma<<<dim3(8, BATCH * 8), dim3(256), 0, stream>>>(qt, kt, vv, av);
  gemm_mfma<2><<<dim3(8, 4, BATCH), dim3(256), 0, stream>>>(
      proj_w, proj_b, (const float*)nullptr, av, (const float*)nullptr, (const float*)nullptr,
      x, (u16*)nullptr, (u16*)nullptr, (u16*)nullptr, out, 0);
}